// Round 21
// baseline (142.920 us; speedup 1.0000x reference)
//
#include <hip/hip_runtime.h>
#include <hip/hip_bf16.h>

#define B_ 256
#define N_ 784
#define E_ 6272
#define C_ 32
#define H_ 512
#define NK 25088            // N_*C_  (K of fc1; wf1t row stride)
#define KP2 832             // padded src-dim for Adj/h1T (13 k-steps of 64)
#define MP 896              // padded dest-dim (7 m-tiles of 128)
#define BC2 8192            // B_*C_ = gemm2 N-dim / agg2 row stride
#define S_SPLIT 28

typedef __attribute__((ext_vector_type(8))) short short8;
typedef __attribute__((ext_vector_type(4))) float f32x4;

__device__ __forceinline__ float elu1(float v) {
  return v > 0.f ? v : (__expf(v) - 1.f);
}

__device__ __forceinline__ unsigned short bf16b(float v) {
  __hip_bfloat16 h = __float2bfloat16(v);
  return *reinterpret_cast<unsigned short*>(&h);
}

__device__ __forceinline__ unsigned int pk2(float lo, float hi) {
  return (unsigned int)bf16b(lo) | ((unsigned int)bf16b(hi) << 16);
}

// ---- K0: block 0 = CSR; blocks 1..91 = zero Adj; blocks 92.. = Wf1 T part1 ----
__global__ __launch_bounds__(1024) void k_prep(
    const int* __restrict__ erow, const int* __restrict__ ecol,
    const float* __restrict__ eval, const float* __restrict__ Wf1,
    int* __restrict__ row_ptr, int* __restrict__ col_s, float* __restrict__ val_s,
    __hip_bfloat16* __restrict__ adj, __hip_bfloat16* __restrict__ wf1t) {
  const int t = threadIdx.x;
  if (blockIdx.x == 0) {
    __shared__ int cnt[N_];
    __shared__ int off[N_];
    __shared__ int bufA[1024];
    __shared__ int bufB[1024];
    if (t < N_) cnt[t] = 0;
    __syncthreads();
    for (int e = t; e < E_; e += 1024) atomicAdd(&cnt[erow[e]], 1);
    __syncthreads();
    bufA[t] = (t < N_) ? cnt[t] : 0;
    __syncthreads();
    int* src = bufA; int* dst = bufB;
    for (int d = 1; d < 1024; d <<= 1) {
      int v = src[t];
      if (t >= d) v += src[t - d];
      dst[t] = v;
      __syncthreads();
      int* tmp = src; src = dst; dst = tmp;
    }
    if (t < N_) {
      int ex = src[t] - cnt[t];
      off[t] = ex;
      row_ptr[t] = ex;
    }
    if (t == 0) row_ptr[N_] = E_;
    __syncthreads();
    for (int e = t; e < E_; e += 1024) {
      int r = erow[e];
      int p = atomicAdd(&off[r], 1);
      col_s[p] = ecol[e];
      val_s[p] = eval[e];
    }
  } else if (blockIdx.x <= 91) {
    // zero Adj [896][832] bf16 = 1,490,944 B (91 blocks x 16384 B)
    size_t off16 = ((size_t)(blockIdx.x - 1) * 1024 + t) * 16;
    if (off16 < (size_t)MP * KP2 * 2) {
      int4 z = {0, 0, 0, 0};
      *reinterpret_cast<int4*>(reinterpret_cast<char*>(adj) + off16) = z;
    }
  } else {
    // Wf1 [25088][512] f32 -> wf1t [512][25088] bf16, k in [0, 12544)
    __shared__ float tile[64][65];
    int bid = blockIdx.x - 92;                 // 0..1567
    int k0 = (bid % 196) * 64, n0 = (bid / 196) * 64;
#pragma unroll
    for (int it = 0; it < 4; ++it) {
      int idx = it * 1024 + t;
      int k = idx >> 6, n = idx & 63;
      tile[k][n] = Wf1[(size_t)(k0 + k) * H_ + n0 + n];
    }
    __syncthreads();
#pragma unroll
    for (int it = 0; it < 2; ++it) {
      int idx = it * 1024 + t;
      int n = idx >> 5, kp = idx & 31;
      unsigned int v = pk2(tile[2 * kp][n], tile[2 * kp + 1][n]);
      *reinterpret_cast<unsigned int*>(
          wf1t + (size_t)(n0 + n) * NK + k0 + 2 * kp) = v;
    }
  }
}

// ---- K1: blocks [0,256): exact-f32 spmm1 + W1 + elu -> h1T[bc][src] (pad 832)
//      blocks [256,260): Adj scatter from CSR (row-owned, duplicate-safe)
//      blocks [260,1828): Wf1 T part2 (k in [12544, 25088)) ----
__global__ __launch_bounds__(256) void k_h1T(
    const float* __restrict__ x, const int* __restrict__ row_ptr,
    const int* __restrict__ col_s, const float* __restrict__ val_s,
    const float* __restrict__ W1, const float* __restrict__ b1,
    const float* __restrict__ Wf1, __hip_bfloat16* __restrict__ adj,
    __hip_bfloat16* __restrict__ wf1t, __hip_bfloat16* __restrict__ h1T) {
  __shared__ float sm[64 * 65];       // union: xls[784]+aggls[784] | 64x65 tile
  int bid = blockIdx.x, t = threadIdx.x;
  if (bid < B_) {
    int b = bid;
    float* xls = sm;
    float* aggls = sm + N_;
    for (int i = t; i < N_; i += 256) xls[i] = x[(size_t)b * N_ + i];
    __syncthreads();
    for (int i = t; i < N_; i += 256) {
      int e0 = row_ptr[i], e1 = row_ptr[i + 1];
      float a = 0.f;
      for (int e = e0; e < e1; ++e) a = fmaf(val_s[e], xls[col_s[e]], a);
      aggls[i] = a;
    }
    __syncthreads();
#pragma unroll
    for (int c = 0; c < C_; ++c) {
      __hip_bfloat16* rowp = h1T + (size_t)(b * C_ + c) * KP2;
      float wc = W1[c], bc = b1[c];
      for (int i = t; i < KP2 / 2; i += 256) {
        int n = 2 * i;
        float v0 = (n < N_) ? elu1(fmaf(aggls[n], wc, bc)) : 0.f;
        float v1 = (n + 1 < N_) ? elu1(fmaf(aggls[n + 1], wc, bc)) : 0.f;
        *reinterpret_cast<unsigned int*>(rowp + n) = pk2(v0, v1);
      }
    }
  } else if (bid < B_ + 4) {
    int n = (bid - B_) * 256 + t;
    if (n < N_) {
      int e0 = row_ptr[n], e1 = row_ptr[n + 1];
      for (int e = e0; e < e1; ++e) {
        __hip_bfloat16* p = adj + (size_t)n * KP2 + col_s[e];
        float cur = __bfloat162float(*p);
        *p = __float2bfloat16(cur + val_s[e]);
      }
    }
  } else {
    // Wf1 transpose: k0 in [12544, 25088), 64x64 tiles with 256 threads
    int bid2 = bid - (B_ + 4);                 // 0..1567
    int k0 = 12544 + (bid2 % 196) * 64, n0 = (bid2 / 196) * 64;
    float (*tile)[65] = reinterpret_cast<float(*)[65]>(sm);
#pragma unroll
    for (int it = 0; it < 16; ++it) {
      int idx = it * 256 + t;
      int kk = idx >> 6, nn = idx & 63;
      tile[kk][nn] = Wf1[(size_t)(k0 + kk) * H_ + n0 + nn];
    }
    __syncthreads();
#pragma unroll
    for (int it = 0; it < 8; ++it) {
      int idx = it * 256 + t;
      int nn = idx >> 5, kp = idx & 31;
      unsigned int v = pk2(tile[2 * kp][nn], tile[2 * kp + 1][nn]);
      *reinterpret_cast<unsigned int*>(
          wf1t + (size_t)(n0 + nn) * NK + k0 + 2 * kp) = v;
    }
  }
}

// ---- K2: spmm2 as dense MFMA GEMM -- fc1 clone + XCD-L2 partitioning ----------
// agg2[m 896][n 8192] = sum_k Adj[m][k] * h1T[n][k], K=832 (13 steps of 64).
// BM=128, BN=64; grid = 896. XCD swizzle: x=raw&7, j=raw>>3; nt=x*16+(j&15),
// mt=j>>4. Each XCD sees 16 fixed n-tiles x all 7 m-tiles -> working set
// (adj 1.5MB + h1T slices 1.7MB) fits 4MB XCD L2; staging re-reads become
// L2 hits (286MB @ 34.5TB/s ~ 8us floor).
__global__ __launch_bounds__(256, 2) void k_gemm2(
    const __hip_bfloat16* __restrict__ adj, const __hip_bfloat16* __restrict__ h1T,
    float* __restrict__ agg2) {
  __shared__ unsigned char lds[3 * 24576];
  int raw = blockIdx.x;
  int xcd = raw & 7, j = raw >> 3;
  int nt = xcd * 16 + (j & 15);
  int mt = j >> 4;
  int m0 = mt * 128;
  int n0 = nt * 64;
  int tid = threadIdx.x;
  int w = tid >> 6, l = tid & 63;
  int r = l & 15, g = l >> 4;

  const __hip_bfloat16* src[6];
  int ldsoff[6];
#pragma unroll
  for (int j2 = 0; j2 < 6; ++j2) {
    int reg = w * 6 + j2;
    ldsoff[j2] = reg * 1024 + l * 16;
    if (reg < 16) {
      int fmg = reg >> 1, ks = reg & 1;
      src[j2] = adj + (size_t)(m0 + fmg * 16 + r) * KP2 + (ks * 32 + g * 8);
    } else {
      int fng = (reg - 16) >> 1, ks = reg & 1;
      src[j2] = h1T + (size_t)(n0 + fng * 16 + r) * KP2 + (ks * 32 + g * 8);
    }
  }

  f32x4 acc[4][2];
#pragma unroll
  for (int i = 0; i < 4; ++i)
#pragma unroll
    for (int j2 = 0; j2 < 2; ++j2) acc[i][j2] = (f32x4){0.f, 0.f, 0.f, 0.f};

#define GLOAD_LDS(gp, lp)                                                     \
  __builtin_amdgcn_global_load_lds(                                           \
      (const __attribute__((address_space(1))) unsigned int*)(gp),            \
      (__attribute__((address_space(3))) unsigned int*)(lp), 16, 0, 0)
#define STAGE(t, buf) do {                                                    \
    _Pragma("unroll")                                                         \
    for (int j2 = 0; j2 < 6; ++j2)                                            \
      GLOAD_LDS(src[j2] + (t) * 64, &lds[(buf) * 24576 + ldsoff[j2]]);        \
  } while (0)
#define VWAIT(n) do {                                                         \
    asm volatile("s_waitcnt vmcnt(%0)" :: "n"(n) : "memory");                 \
    __builtin_amdgcn_sched_barrier(0);                                        \
  } while (0)
#define BAR() do {                                                            \
    __builtin_amdgcn_s_barrier();                                             \
    __builtin_amdgcn_sched_barrier(0);                                        \
  } while (0)
#define COMPUTE(buf) do {                                                     \
    const unsigned char* bb = &lds[(buf) * 24576];                            \
    short8 af[4][2], bf[2][2];                                                \
    _Pragma("unroll")                                                         \
    for (int fm = 0; fm < 4; ++fm)                                            \
      _Pragma("unroll")                                                       \
      for (int ks = 0; ks < 2; ++ks)                                          \
        af[fm][ks] = *reinterpret_cast<const short8*>(                        \
            bb + (((4 * (w & 1) + fm) * 2 + ks) << 10) + l * 16);             \
    _Pragma("unroll")                                                         \
    for (int fn = 0; fn < 2; ++fn)                                            \
      _Pragma("unroll")                                                       \
      for (int ks = 0; ks < 2; ++ks)                                          \
        bf[fn][ks] = *reinterpret_cast<const short8*>(                        \
            bb + ((16 + (2 * (w >> 1) + fn) * 2 + ks) << 10) + l * 16);       \
    _Pragma("unroll")                                                         \
    for (int ks = 0; ks < 2; ++ks)                                            \
      _Pragma("unroll")                                                       \
      for (int fn = 0; fn < 2; ++fn)                                          \
        _Pragma("unroll")                                                     \
        for (int fm = 0; fm < 4; ++fm)                                        \
          acc[fm][fn] = __builtin_amdgcn_mfma_f32_16x16x32_bf16(              \
              af[fm][ks], bf[fn][ks], acc[fm][fn], 0, 0, 0);                  \
  } while (0)
#define STEP(t) do {                                                          \
    VWAIT((t) < 12 ? 6 : 0);                                                  \
    BAR();                                                                    \
    if ((t) + 2 <= 12) STAGE((t) + 2, ((t) + 2) % 3);                         \
    COMPUTE((t) % 3);                                                         \
  } while (0)

  STAGE(0, 0);
  STAGE(1, 1);
  STEP(0);  STEP(1);  STEP(2);  STEP(3);  STEP(4);  STEP(5);  STEP(6);
  STEP(7);  STEP(8);  STEP(9);  STEP(10); STEP(11); STEP(12);

#undef GLOAD_LDS
#undef STAGE
#undef VWAIT
#undef BAR
#undef COMPUTE
#undef STEP

  int wm = (w & 1) * 64, wn = (w >> 1) * 32;
#pragma unroll
  for (int fm = 0; fm < 4; ++fm)
#pragma unroll
    for (int fn = 0; fn < 2; ++fn)
#pragma unroll
      for (int q = 0; q < 4; ++q) {
        int m = m0 + wm + fm * 16 + g * 4 + q;
        int n = n0 + wn + fn * 16 + r;
        agg2[(size_t)m * BC2 + n] = acc[fm][fn][q];
      }
}

// ---- K2b: W2 apply + elu + bf16 -> flat (elementwise, trivial pressure) -------
__global__ __launch_bounds__(256) void k_w2(
    const float* __restrict__ agg2, const float* __restrict__ W2,
    const float* __restrict__ b2, __hip_bfloat16* __restrict__ flat) {
  __shared__ float w2s[C_][C_ + 1];
  __shared__ float b2s[C_];
  int n = blockIdx.x, t = threadIdx.x;
  for (int i = t; i < C_ * C_; i += 256) w2s[i >> 5][i & 31] = W2[i];
  if (t < C_) b2s[t] = b2[t];
  __syncthreads();
  const float* arow = agg2 + (size_t)n * BC2 + t * C_;
  float a[C_];
#pragma unroll
  for (int j = 0; j < 8; ++j) {
    f32x4 v = *reinterpret_cast<const f32x4*>(arow + j * 4);
    a[j * 4 + 0] = v[0]; a[j * 4 + 1] = v[1];
    a[j * 4 + 2] = v[2]; a[j * 4 + 3] = v[3];
  }
  union { unsigned short u[C_]; int4 v[4]; } ob;
#pragma unroll
  for (int c = 0; c < C_; c += 2) {
    float o0 = b2s[c], o1 = b2s[c + 1];
#pragma unroll
    for (int cc = 0; cc < C_; ++cc) {
      o0 = fmaf(a[cc], w2s[cc][c], o0);
      o1 = fmaf(a[cc], w2s[cc][c + 1], o1);
    }
    ob.u[c] = bf16b(elu1(o0));
    ob.u[c + 1] = bf16b(elu1(o1));
  }
  int4* dst = reinterpret_cast<int4*>(flat + (size_t)t * NK + n * C_);
#pragma unroll
  for (int j = 0; j < 4; ++j) dst[j] = ob.v[j];
}

// ---------------- K3: fc1 split-K MFMA GEMM via global_load_lds pipeline ----------
// (unchanged from round 10 -- verified working)
__global__ __launch_bounds__(256, 2) void k_fc1(
    const __hip_bfloat16* __restrict__ flat, const __hip_bfloat16* __restrict__ wf1t,
    float* __restrict__ partial) {
  __shared__ unsigned char lds[3 * 24576];
  int raw = blockIdx.x;
  int bid = (raw & 7) * 56 + (raw >> 3);      // bijective XCD swizzle (448 = 8*56)
  int s = bid >> 4, r16 = bid & 15;
  int m0 = (r16 & 1) * 128;
  int n0 = (r16 >> 1) * 64;
  int k0 = s * 896;
  int tid = threadIdx.x;
  int w = tid >> 6, l = tid & 63;
  int r = l & 15, g = l >> 4;

  const __hip_bfloat16* src[6];
  int ldsoff[6];
#pragma unroll
  for (int j = 0; j < 6; ++j) {
    int reg = w * 6 + j;
    ldsoff[j] = reg * 1024 + l * 16;
    if (reg < 16) {
      int fmg = reg >> 1, ks = reg & 1;
      src[j] = flat + (size_t)(m0 + fmg * 16 + r) * NK + (k0 + ks * 32 + g * 8);
    } else {
      int fng = (reg - 16) >> 1, ks = reg & 1;
      src[j] = wf1t + (size_t)(n0 + fng * 16 + r) * NK + (k0 + ks * 32 + g * 8);
    }
  }

  f32x4 acc[4][2];
#pragma unroll
  for (int i = 0; i < 4; ++i)
#pragma unroll
    for (int j = 0; j < 2; ++j) acc[i][j] = (f32x4){0.f, 0.f, 0.f, 0.f};

#define GLOAD_LDS(gp, lp)                                                     \
  __builtin_amdgcn_global_load_lds(                                           \
      (const __attribute__((address_space(1))) unsigned int*)(gp),            \
      (__attribute__((address_space(3))) unsigned int*)(lp), 16, 0, 0)
#define STAGE(t, buf) do {                                                    \
    _Pragma("unroll")                                                         \
    for (int j = 0; j < 6; ++j)                                               \
      GLOAD_LDS(src[j] + (t) * 64, &lds[(buf) * 24576 + ldsoff[j]]);          \
  } while (0)
#define VWAIT(n) do {                                                         \
    asm volatile("s_waitcnt vmcnt(%0)" :: "n"(n) : "memory");                 \
    __builtin_amdgcn_sched_barrier(0);                                        \
  } while (0)
#define BAR() do {                                                            \
    __builtin_amdgcn_s_barrier();                                             \
    __builtin_amdgcn_sched_barrier(0);                                        \
  } while (0)
#define COMPUTE(buf) do {                                                     \
    const unsigned char* bb = &lds[(buf) * 24576];                            \
    short8 af[4][2], bf[2][2];                                                \
    _Pragma("unroll")                                                         \
    for (int fm = 0; fm < 4; ++fm)                                            \
      _Pragma("unroll")                                                       \
      for (int ks = 0; ks < 2; ++ks)                                          \
        af[fm][ks] = *reinterpret_cast<const short8*>(                        \
            bb + (((4 * (w & 1) + fm) * 2 + ks) << 10) + l * 16);             \
    _Pragma("unroll")                                                         \
    for (int fn = 0; fn < 2; ++fn)                                            \
      _Pragma("unroll")                                                       \
      for (int ks = 0; ks < 2; ++ks)                                          \
        bf[fn][ks] = *reinterpret_cast<const short8*>(                        \
            bb + ((16 + (2 * (w >> 1) + fn) * 2 + ks) << 10) + l * 16);       \
    _Pragma("unroll")                                                         \
    for (int ks = 0; ks < 2; ++ks)                                            \
      _Pragma("unroll")                                                       \
      for (int fn = 0; fn < 2; ++fn)                                          \
        _Pragma("unroll")                                                     \
        for (int fm = 0; fm < 4; ++fm)                                        \
          acc[fm][fn] = __builtin_amdgcn_mfma_f32_16x16x32_bf16(              \
              af[fm][ks], bf[fn][ks], acc[fm][fn], 0, 0, 0);                  \
  } while (0)
#define STEP(t) do {                                                          \
    VWAIT((t) < 13 ? 6 : 0);                                                  \
    BAR();                                                                    \
    if ((t) + 2 <= 13) STAGE((t) + 2, ((t) + 2) % 3);                         \
    COMPUTE((t) % 3);                                                         \
  } while (0)

  STAGE(0, 0);
  STAGE(1, 1);
  STEP(0);  STEP(1);  STEP(2);  STEP(3);  STEP(4);  STEP(5);  STEP(6);
  STEP(7);  STEP(8);  STEP(9);  STEP(10); STEP(11); STEP(12); STEP(13);

#undef GLOAD_LDS
#undef STAGE
#undef VWAIT
#undef BAR
#undef COMPUTE
#undef STEP

  int wm = (w & 1) * 64, wn = (w >> 1) * 32;
  float* p = partial + (size_t)s * (256 * 512);
#pragma unroll
  for (int fm = 0; fm < 4; ++fm)
#pragma unroll
    for (int fn = 0; fn < 2; ++fn)
#pragma unroll
      for (int q = 0; q < 4; ++q) {
        int m = m0 + wm + fm * 16 + g * 4 + q;
        int n = n0 + wn + fn * 16 + r;
        p[m * 512 + n] = acc[fm][fn][q];
      }
}

// ---------------- K4: reduce partials + bias + relu + fc2 + softmax ----------------
__global__ __launch_bounds__(512) void k_head(
    const float* __restrict__ partial, const float* __restrict__ bf1,
    const float* __restrict__ Wf2, const float* __restrict__ bf2,
    float* __restrict__ out) {
  __shared__ float red[8][12];
  int b = blockIdx.x;
  int t = threadIdx.x;
  float v = bf1[t];
#pragma unroll
  for (int s = 0; s < S_SPLIT; ++s)
    v += partial[(size_t)s * (256 * 512) + b * 512 + t];
  v = fmaxf(v, 0.f);
  float pacc[10];
#pragma unroll
  for (int j = 0; j < 10; ++j) pacc[j] = v * Wf2[t * 10 + j];
#pragma unroll
  for (int j = 0; j < 10; ++j)
#pragma unroll
    for (int d = 32; d > 0; d >>= 1)
      pacc[j] += __shfl_down(pacc[j], d);
  int wv = t >> 6, ln = t & 63;
  if (ln == 0) {
#pragma unroll
    for (int j = 0; j < 10; ++j) red[wv][j] = pacc[j];
  }
  __syncthreads();
  if (t == 0) {
    float lg[10];
    float m = -1e30f;
#pragma unroll
    for (int j = 0; j < 10; ++j) {
      float z = bf2[j];
#pragma unroll
      for (int wq = 0; wq < 8; ++wq) z += red[wq][j];
      lg[j] = z;
      m = fmaxf(m, z);
    }
    float sum = 0.f;
#pragma unroll
    for (int j = 0; j < 10; ++j) { lg[j] = __expf(lg[j] - m); sum += lg[j]; }
    float inv = 1.f / sum;
#pragma unroll
    for (int j = 0; j < 10; ++j) out[b * 10 + j] = lg[j] * inv;
  }
}

extern "C" void kernel_launch(void* const* d_in, const int* in_sizes, int n_in,
                              void* d_out, int out_size, void* d_ws, size_t ws_size,
                              hipStream_t stream) {
  const float* x    = (const float*)d_in[0];
  const int*   erow = (const int*)d_in[1];
  const int*   ecol = (const int*)d_in[2];
  const float* ev   = (const float*)d_in[3];
  const float* W1   = (const float*)d_in[4];
  const float* b1   = (const float*)d_in[5];
  const float* W2   = (const float*)d_in[6];
  const float* b2   = (const float*)d_in[7];
  const float* Wf1  = (const float*)d_in[8];
  const float* bf1  = (const float*)d_in[9];
  const float* Wf2  = (const float*)d_in[10];
  const float* bf2  = (const float*)d_in[11];
  float* out = (float*)d_out;

  const size_t partial_bytes = (size_t)S_SPLIT * 256 * 512 * 4;   // 14,680,064
  const size_t flat_bytes    = (size_t)B_ * NK * 2;               // 12,845,056
  const size_t wf1t_bytes    = (size_t)H_ * NK * 2;               // 25,690,112
  const size_t h1t_bytes     = (size_t)B_ * C_ * KP2 * 2;         // 13,631,488
  const size_t adj_bytes     = (size_t)MP * KP2 * 2;              //  1,490,944
  const size_t agg2_bytes    = (size_t)MP * BC2 * 4;              // 29,360,128

  // disjoint layout (~98 MB; ws is ~268 MB)
  char* ws = (char*)d_ws;
  float* partial          = (float*)ws;
  __hip_bfloat16* flat    = (__hip_bfloat16*)(ws + partial_bytes);
  __hip_bfloat16* wf1t    = (__hip_bfloat16*)(ws + partial_bytes + flat_bytes);
  __hip_bfloat16* h1T     = (__hip_bfloat16*)(ws + partial_bytes + flat_bytes + wf1t_bytes);
  __hip_bfloat16* adj     = (__hip_bfloat16*)(ws + partial_bytes + flat_bytes + wf1t_bytes + h1t_bytes);
  float* agg2             = (float*)(ws + partial_bytes + flat_bytes + wf1t_bytes + h1t_bytes + adj_bytes);
  char* tail = ws + partial_bytes + flat_bytes + wf1t_bytes + h1t_bytes + adj_bytes + agg2_bytes;
  int*   row_ptr = (int*)tail;
  int*   col_s   = (int*)(tail + 3152);
  float* val_s   = (float*)(tail + 3152 + E_ * 4);

  hipLaunchKernelGGL(k_prep, dim3(1 + 91 + 1568), dim3(1024), 0, stream,
                     erow, ecol, ev, Wf1, row_ptr, col_s, val_s, adj, wf1t);
  hipLaunchKernelGGL(k_h1T, dim3(B_ + 4 + 1568), dim3(256), 0, stream,
                     x, row_ptr, col_s, val_s, W1, b1, Wf1, adj, wf1t, h1T);
  hipLaunchKernelGGL(k_gemm2, dim3(MP / 128 * 128), dim3(256), 0, stream,
                     adj, h1T, agg2);
  hipLaunchKernelGGL(k_w2, dim3(N_), dim3(256), 0, stream,
                     agg2, W2, b2, flat);
  hipLaunchKernelGGL(k_fc1, dim3(S_SPLIT * 16), dim3(256), 0, stream,
                     flat, wf1t, partial);
  hipLaunchKernelGGL(k_head, dim3(B_), dim3(512), 0, stream,
                     partial, bf1, Wf2, bf2, out);
}

// Round 22
// 94.295 us; speedup vs baseline: 1.5157x; 1.5157x over previous
//
#include <hip/hip_runtime.h>
#include <hip/hip_bf16.h>

#define B_ 256
#define N_ 784
#define E_ 6272
#define C_ 32
#define H_ 512
#define NK 25088            // N_*C_  (K of fc1; wf1t row stride)
#define BC 8192             // B_*C_ (h1 node stride)
#define S_SPLIT 28

typedef __attribute__((ext_vector_type(8))) short short8;
typedef __attribute__((ext_vector_type(4))) float f32x4;

__device__ __forceinline__ float elu1(float v) {
  return v > 0.f ? v : (__expf(v) - 1.f);
}

__device__ __forceinline__ unsigned short bf16b(float v) {
  __hip_bfloat16 h = __float2bfloat16(v);
  return *reinterpret_cast<unsigned short*>(&h);
}

__device__ __forceinline__ unsigned int pk2(float lo, float hi) {
  return (unsigned int)bf16b(lo) | ((unsigned int)bf16b(hi) << 16);
}

__device__ __forceinline__ void acc2(unsigned u, float val, float& a0, float& a1) {
  float lo = __uint_as_float(u << 16);
  float hi = __uint_as_float(u & 0xffff0000u);
  a0 = fmaf(val, lo, a0);
  a1 = fmaf(val, hi, a1);
}

// ---- K0: block 0 = CSR; blocks 1..200 = x transpose ----
__global__ __launch_bounds__(1024) void k_prep(
    const int* __restrict__ erow, const int* __restrict__ ecol,
    const float* __restrict__ eval, const float* __restrict__ x,
    int* __restrict__ row_ptr, int* __restrict__ col_s, float* __restrict__ val_s,
    float* __restrict__ xT) {
  const int t = threadIdx.x;
  if (blockIdx.x == 0) {
    __shared__ int cnt[N_];
    __shared__ int off[N_];
    __shared__ int bufA[1024];
    __shared__ int bufB[1024];
    if (t < N_) cnt[t] = 0;
    __syncthreads();
    for (int e = t; e < E_; e += 1024) atomicAdd(&cnt[erow[e]], 1);
    __syncthreads();
    bufA[t] = (t < N_) ? cnt[t] : 0;
    __syncthreads();
    int* src = bufA; int* dst = bufB;
    for (int d = 1; d < 1024; d <<= 1) {
      int v = src[t];
      if (t >= d) v += src[t - d];
      dst[t] = v;
      __syncthreads();
      int* tmp = src; src = dst; dst = tmp;
    }
    if (t < N_) {
      int ex = src[t] - cnt[t];
      off[t] = ex;
      row_ptr[t] = ex;
    }
    if (t == 0) row_ptr[N_] = E_;
    __syncthreads();
    for (int e = t; e < E_; e += 1024) {
      int r = erow[e];
      int p = atomicAdd(&off[r], 1);
      col_s[p] = ecol[e];
      val_s[p] = eval[e];
    }
  } else {
    __shared__ float tile[32][33];
    int bid = blockIdx.x - 1;
    int n0 = (bid % 25) * 32, b0 = (bid / 25) * 32;
    int ni = t & 31, bi = t >> 5;
    int n = n0 + ni;
    if (n < N_) tile[ni][bi] = x[(b0 + bi) * N_ + n];
    __syncthreads();
    int nj = t >> 5, bj = t & 31;
    int nw = n0 + nj;
    if (nw < N_) xT[nw * B_ + b0 + bj] = tile[nj][bj];
  }
}

// ---- K1: blocks [0,784): spmm1 + W1 + elu -> h1[n][b*32+c]
//      blocks [784,3920): FULL Wf1 cvt+transpose (392 k-tiles x 8 n-tiles, 64x64) ----
__global__ __launch_bounds__(256) void k_gc1(
    const float* __restrict__ xT, const int* __restrict__ row_ptr,
    const int* __restrict__ col_s, const float* __restrict__ val_s,
    const float* __restrict__ W1, const float* __restrict__ b1,
    const float* __restrict__ Wf1, __hip_bfloat16* __restrict__ wf1t,
    __hip_bfloat16* __restrict__ h1) {
  __shared__ union {
    struct { int lc[64]; float lv[64]; } g;
    float tile[64][65];
  } sm;
  int t = threadIdx.x;
  if (blockIdx.x < N_) {
    int n = blockIdx.x;
    int e0 = row_ptr[n], deg = row_ptr[n + 1] - e0;
    float agg = 0.f;
    for (int base = 0; base < deg; base += 64) {
      int m = min(64, deg - base);
      __syncthreads();
      if (t < m) { sm.g.lc[t] = col_s[e0 + base + t]; sm.g.lv[t] = val_s[e0 + base + t]; }
      __syncthreads();
      int e = 0;
      for (; e + 4 <= m; e += 4) {
        float x0 = xT[sm.g.lc[e + 0] * B_ + t];
        float x1 = xT[sm.g.lc[e + 1] * B_ + t];
        float x2 = xT[sm.g.lc[e + 2] * B_ + t];
        float x3 = xT[sm.g.lc[e + 3] * B_ + t];
        agg = fmaf(sm.g.lv[e + 0], x0, agg);
        agg = fmaf(sm.g.lv[e + 1], x1, agg);
        agg = fmaf(sm.g.lv[e + 2], x2, agg);
        agg = fmaf(sm.g.lv[e + 3], x3, agg);
      }
      for (; e < m; ++e)
        agg = fmaf(sm.g.lv[e], xT[sm.g.lc[e] * B_ + t], agg);
    }
    union { unsigned int u[16]; uint4 v[4]; } ob;
#pragma unroll
    for (int c = 0; c < C_; c += 2) {
      float o0 = elu1(fmaf(agg, W1[c], b1[c]));
      float o1 = elu1(fmaf(agg, W1[c + 1], b1[c + 1]));
      ob.u[c >> 1] = pk2(o0, o1);
    }
    uint4* dst = reinterpret_cast<uint4*>(h1 + (size_t)n * BC + t * C_);
#pragma unroll
    for (int j = 0; j < 4; ++j) dst[j] = ob.v[j];
  } else {
    // Full Wf1 transpose: 392 k-tiles x 8 n-tiles of 64x64, 256 threads each
    int bid = blockIdx.x - N_;                 // 0..3135
    int k0 = (bid % 392) * 64, n0 = (bid / 392) * 64;
#pragma unroll
    for (int it = 0; it < 16; ++it) {
      int idx = it * 256 + t;
      int kk = idx >> 6, nn = idx & 63;
      sm.tile[kk][nn] = Wf1[(size_t)(k0 + kk) * H_ + n0 + nn];
    }
    __syncthreads();
#pragma unroll
    for (int it = 0; it < 8; ++it) {
      int idx = it * 256 + t;
      int nn = idx >> 5, kp = idx & 31;
      unsigned int v = pk2(sm.tile[2 * kp][nn], sm.tile[2 * kp + 1][nn]);
      *reinterpret_cast<unsigned int*>(
          wf1t + (size_t)(n0 + nn) * NK + k0 + 2 * kp) = v;
    }
  }
}

// ---- K2: PURE spmm2 gather + W2 + elu -> flat (q=bid&3, n=bid>>2) ----
__global__ __launch_bounds__(64) void k_gc2(
    const __hip_bfloat16* __restrict__ h1, const int* __restrict__ row_ptr,
    const int* __restrict__ col_s, const float* __restrict__ val_s,
    const float* __restrict__ W2, const float* __restrict__ b2,
    __hip_bfloat16* __restrict__ flat) {
  __shared__ int lc[64];
  __shared__ float lv[64];
  int bid = blockIdx.x;
  int q = bid & 3;
  int n = bid >> 2;
  int t = threadIdx.x;
  int tb = q * 64 + t;
  int e0 = row_ptr[n], deg = row_ptr[n + 1] - e0;
  float acc[C_];
#pragma unroll
  for (int c = 0; c < C_; ++c) acc[c] = 0.f;

#define ACC16(v0, v1, v2, v3, val) do {                                       \
    acc2(v0.x, val, acc[0], acc[1]);  acc2(v0.y, val, acc[2], acc[3]);        \
    acc2(v0.z, val, acc[4], acc[5]);  acc2(v0.w, val, acc[6], acc[7]);        \
    acc2(v1.x, val, acc[8], acc[9]);  acc2(v1.y, val, acc[10], acc[11]);      \
    acc2(v1.z, val, acc[12], acc[13]); acc2(v1.w, val, acc[14], acc[15]);     \
    acc2(v2.x, val, acc[16], acc[17]); acc2(v2.y, val, acc[18], acc[19]);     \
    acc2(v2.z, val, acc[20], acc[21]); acc2(v2.w, val, acc[22], acc[23]);     \
    acc2(v3.x, val, acc[24], acc[25]); acc2(v3.y, val, acc[26], acc[27]);     \
    acc2(v3.z, val, acc[28], acc[29]); acc2(v3.w, val, acc[30], acc[31]);     \
  } while (0)

  for (int base = 0; base < deg; base += 64) {
    int m = min(64, deg - base);
    __syncthreads();
    if (t < m) { lc[t] = col_s[e0 + base + t]; lv[t] = val_s[e0 + base + t]; }
    __syncthreads();
    int e = 0;
    for (; e + 4 <= m; e += 4) {
      const uint4* p0 = reinterpret_cast<const uint4*>(h1 + (size_t)lc[e + 0] * BC + tb * C_);
      const uint4* p1 = reinterpret_cast<const uint4*>(h1 + (size_t)lc[e + 1] * BC + tb * C_);
      const uint4* p2 = reinterpret_cast<const uint4*>(h1 + (size_t)lc[e + 2] * BC + tb * C_);
      const uint4* p3 = reinterpret_cast<const uint4*>(h1 + (size_t)lc[e + 3] * BC + tb * C_);
      uint4 a0 = p0[0], a1 = p0[1], a2 = p0[2], a3 = p0[3];
      uint4 b0 = p1[0], b1 = p1[1], b2v = p1[2], b3 = p1[3];
      uint4 c0 = p2[0], c1 = p2[1], c2 = p2[2], c3 = p2[3];
      uint4 d0 = p3[0], d1 = p3[1], d2 = p3[2], d3 = p3[3];
      float va = lv[e], vb = lv[e + 1], vc = lv[e + 2], vd = lv[e + 3];
      ACC16(a0, a1, a2, a3, va);
      ACC16(b0, b1, b2v, b3, vb);
      ACC16(c0, c1, c2, c3, vc);
      ACC16(d0, d1, d2, d3, vd);
    }
    for (; e < m; ++e) {
      const uint4* p0 = reinterpret_cast<const uint4*>(h1 + (size_t)lc[e] * BC + tb * C_);
      uint4 a0 = p0[0], a1 = p0[1], a2 = p0[2], a3 = p0[3];
      ACC16(a0, a1, a2, a3, lv[e]);
    }
  }
#undef ACC16

  union { unsigned int u[16]; uint4 v[4]; } ob;
#pragma unroll
  for (int c2 = 0; c2 < C_; c2 += 2) {
    float o0 = b2[c2], o1 = b2[c2 + 1];
#pragma unroll
    for (int c = 0; c < C_; ++c) {
      o0 = fmaf(acc[c], W2[c * C_ + c2], o0);
      o1 = fmaf(acc[c], W2[c * C_ + c2 + 1], o1);
    }
    ob.u[c2 >> 1] = pk2(elu1(o0), elu1(o1));
  }
  uint4* dst = reinterpret_cast<uint4*>(flat + (size_t)tb * NK + n * C_);
#pragma unroll
  for (int j = 0; j < 4; ++j) dst[j] = ob.v[j];
}

// ---------------- K3: fc1 split-K MFMA GEMM via global_load_lds pipeline ----------
// (unchanged from round 10 -- verified working)
__global__ __launch_bounds__(256, 2) void k_fc1(
    const __hip_bfloat16* __restrict__ flat, const __hip_bfloat16* __restrict__ wf1t,
    float* __restrict__ partial) {
  __shared__ unsigned char lds[3 * 24576];
  int raw = blockIdx.x;
  int bid = (raw & 7) * 56 + (raw >> 3);      // bijective XCD swizzle (448 = 8*56)
  int s = bid >> 4, r16 = bid & 15;
  int m0 = (r16 & 1) * 128;
  int n0 = (r16 >> 1) * 64;
  int k0 = s * 896;
  int tid = threadIdx.x;
  int w = tid >> 6, l = tid & 63;
  int r = l & 15, g = l >> 4;

  const __hip_bfloat16* src[6];
  int ldsoff[6];
#pragma unroll
  for (int j = 0; j < 6; ++j) {
    int reg = w * 6 + j;
    ldsoff[j] = reg * 1024 + l * 16;
    if (reg < 16) {
      int fmg = reg >> 1, ks = reg & 1;
      src[j] = flat + (size_t)(m0 + fmg * 16 + r) * NK + (k0 + ks * 32 + g * 8);
    } else {
      int fng = (reg - 16) >> 1, ks = reg & 1;
      src[j] = wf1t + (size_t)(n0 + fng * 16 + r) * NK + (k0 + ks * 32 + g * 8);
    }
  }

  f32x4 acc[4][2];
#pragma unroll
  for (int i = 0; i < 4; ++i)
#pragma unroll
    for (int j = 0; j < 2; ++j) acc[i][j] = (f32x4){0.f, 0.f, 0.f, 0.f};

#define GLOAD_LDS(gp, lp)                                                     \
  __builtin_amdgcn_global_load_lds(                                           \
      (const __attribute__((address_space(1))) unsigned int*)(gp),            \
      (__attribute__((address_space(3))) unsigned int*)(lp), 16, 0, 0)
#define STAGE(t, buf) do {                                                    \
    _Pragma("unroll")                                                         \
    for (int j = 0; j < 6; ++j)                                               \
      GLOAD_LDS(src[j] + (t) * 64, &lds[(buf) * 24576 + ldsoff[j]]);          \
  } while (0)
#define VWAIT(n) do {                                                         \
    asm volatile("s_waitcnt vmcnt(%0)" :: "n"(n) : "memory");                 \
    __builtin_amdgcn_sched_barrier(0);                                        \
  } while (0)
#define BAR() do {                                                            \
    __builtin_amdgcn_s_barrier();                                             \
    __builtin_amdgcn_sched_barrier(0);                                        \
  } while (0)
#define COMPUTE(buf) do {                                                     \
    const unsigned char* bb = &lds[(buf) * 24576];                            \
    short8 af[4][2], bf[2][2];                                                \
    _Pragma("unroll")                                                         \
    for (int fm = 0; fm < 4; ++fm)                                            \
      _Pragma("unroll")                                                       \
      for (int ks = 0; ks < 2; ++ks)                                          \
        af[fm][ks] = *reinterpret_cast<const short8*>(                        \
            bb + (((4 * (w & 1) + fm) * 2 + ks) << 10) + l * 16);             \
    _Pragma("unroll")                                                         \
    for (int fn = 0; fn < 2; ++fn)                                            \
      _Pragma("unroll")                                                       \
      for (int ks = 0; ks < 2; ++ks)                                          \
        bf[fn][ks] = *reinterpret_cast<const short8*>(                        \
            bb + ((16 + (2 * (w >> 1) + fn) * 2 + ks) << 10) + l * 16);       \
    _Pragma("unroll")                                                         \
    for (int ks = 0; ks < 2; ++ks)                                            \
      _Pragma("unroll")                                                       \
      for (int fn = 0; fn < 2; ++fn)                                          \
        _Pragma("unroll")                                                     \
        for (int fm = 0; fm < 4; ++fm)                                        \
          acc[fm][fn] = __builtin_amdgcn_mfma_f32_16x16x32_bf16(              \
              af[fm][ks], bf[fn][ks], acc[fm][fn], 0, 0, 0);                  \
  } while (0)
#define STEP(t) do {                                                          \
    VWAIT((t) < 13 ? 6 : 0);                                                  \
    BAR();                                                                    \
    if ((t) + 2 <= 13) STAGE((t) + 2, ((t) + 2) % 3);                         \
    COMPUTE((t) % 3);                                                         \
  } while (0)

  STAGE(0, 0);
  STAGE(1, 1);
  STEP(0);  STEP(1);  STEP(2);  STEP(3);  STEP(4);  STEP(5);  STEP(6);
  STEP(7);  STEP(8);  STEP(9);  STEP(10); STEP(11); STEP(12); STEP(13);

#undef GLOAD_LDS
#undef STAGE
#undef VWAIT
#undef BAR
#undef COMPUTE
#undef STEP

  int wm = (w & 1) * 64, wn = (w >> 1) * 32;
  float* p = partial + (size_t)s * (256 * 512);
#pragma unroll
  for (int fm = 0; fm < 4; ++fm)
#pragma unroll
    for (int fn = 0; fn < 2; ++fn)
#pragma unroll
      for (int q = 0; q < 4; ++q) {
        int m = m0 + wm + fm * 16 + g * 4 + q;
        int n = n0 + wn + fn * 16 + r;
        p[m * 512 + n] = acc[fm][fn][q];
      }
}

// ---------------- K4: reduce partials + bias + relu + fc2 + softmax ----------------
__global__ __launch_bounds__(512) void k_head(
    const float* __restrict__ partial, const float* __restrict__ bf1,
    const float* __restrict__ Wf2, const float* __restrict__ bf2,
    float* __restrict__ out) {
  __shared__ float red[8][12];
  int b = blockIdx.x;
  int t = threadIdx.x;
  float v = bf1[t];
#pragma unroll
  for (int s = 0; s < S_SPLIT; ++s)
    v += partial[(size_t)s * (256 * 512) + b * 512 + t];
  v = fmaxf(v, 0.f);
  float pacc[10];
#pragma unroll
  for (int j = 0; j < 10; ++j) pacc[j] = v * Wf2[t * 10 + j];
#pragma unroll
  for (int j = 0; j < 10; ++j)
#pragma unroll
    for (int d = 32; d > 0; d >>= 1)
      pacc[j] += __shfl_down(pacc[j], d);
  int wv = t >> 6, ln = t & 63;
  if (ln == 0) {
#pragma unroll
    for (int j = 0; j < 10; ++j) red[wv][j] = pacc[j];
  }
  __syncthreads();
  if (t == 0) {
    float lg[10];
    float m = -1e30f;
#pragma unroll
    for (int j = 0; j < 10; ++j) {
      float z = bf2[j];
#pragma unroll
      for (int wq = 0; wq < 8; ++wq) z += red[wq][j];
      lg[j] = z;
      m = fmaxf(m, z);
    }
    float sum = 0.f;
#pragma unroll
    for (int j = 0; j < 10; ++j) { lg[j] = __expf(lg[j] - m); sum += lg[j]; }
    float inv = 1.f / sum;
#pragma unroll
    for (int j = 0; j < 10; ++j) out[b * 10 + j] = lg[j] * inv;
  }
}

extern "C" void kernel_launch(void* const* d_in, const int* in_sizes, int n_in,
                              void* d_out, int out_size, void* d_ws, size_t ws_size,
                              hipStream_t stream) {
  const float* x    = (const float*)d_in[0];
  const int*   erow = (const int*)d_in[1];
  const int*   ecol = (const int*)d_in[2];
  const float* ev   = (const float*)d_in[3];
  const float* W1   = (const float*)d_in[4];
  const float* b1   = (const float*)d_in[5];
  const float* W2   = (const float*)d_in[6];
  const float* b2   = (const float*)d_in[7];
  const float* Wf1  = (const float*)d_in[8];
  const float* bf1  = (const float*)d_in[9];
  const float* Wf2  = (const float*)d_in[10];
  const float* bf2  = (const float*)d_in[11];
  float* out = (float*)d_out;

  const size_t partial_bytes = (size_t)S_SPLIT * 256 * 512 * 4;   // 14,680,064
  const size_t flat_bytes    = (size_t)B_ * NK * 2;               // 12,845,056
  const size_t wf1t_bytes    = (size_t)H_ * NK * 2;               // 25,690,112

  // ws layout (~53.3 MB):
  //   [0, 14.68M)          partial   (first 13.7MB doubles as xT+h1, dead before fc1)
  //   [14.68M, 27.53M)     flat bf16
  //   [27.53M, 53.22M)     wf1t bf16 (Wf1 transposed)
  //   tail                 CSR (row_ptr, col_s, val_s)
  char* ws = (char*)d_ws;
  float* partial = (float*)ws;
  float* xT = (float*)ws;
  __hip_bfloat16* h1 = (__hip_bfloat16*)(ws + 802816);
  __hip_bfloat16* flat = (__hip_bfloat16*)(ws + partial_bytes);
  __hip_bfloat16* wf1t = (__hip_bfloat16*)(ws + partial_bytes + flat_bytes);
  char* tail = ws + partial_bytes + flat_bytes + wf1t_bytes;
  int*   row_ptr = (int*)tail;
  int*   col_s   = (int*)(tail + 3152);
  float* val_s   = (float*)(tail + 3152 + E_ * 4);

  hipLaunchKernelGGL(k_prep, dim3(1 + 200), dim3(1024), 0, stream,
                     erow, ecol, ev, x, row_ptr, col_s, val_s, xT);
  hipLaunchKernelGGL(k_gc1, dim3(N_ + 392 * 8), dim3(256), 0, stream,
                     xT, row_ptr, col_s, val_s, W1, b1, Wf1, wf1t, h1);
  hipLaunchKernelGGL(k_gc2, dim3(N_ * 4), dim3(64), 0, stream,
                     h1, row_ptr, col_s, val_s, W2, b2, flat);
  hipLaunchKernelGGL(k_fc1, dim3(S_SPLIT * 16), dim3(256), 0, stream,
                     flat, wf1t, partial);
  hipLaunchKernelGGL(k_head, dim3(B_), dim3(512), 0, stream,
                     partial, bf1, Wf2, bf2, out);
}

// Round 23
// 85.594 us; speedup vs baseline: 1.6697x; 1.1017x over previous
//
#include <hip/hip_runtime.h>
#include <hip/hip_bf16.h>

#define B_ 256
#define N_ 784
#define E_ 6272
#define C_ 32
#define H_ 512
#define NK 25088            // N_*C_  (K of fc1; wf1t row stride)
#define S_SPLIT 28

typedef __attribute__((ext_vector_type(8))) short short8;
typedef __attribute__((ext_vector_type(4))) float f32x4;

__device__ __forceinline__ float elu1(float v) {
  return v > 0.f ? v : (__expf(v) - 1.f);
}

__device__ __forceinline__ unsigned short bf16b(float v) {
  __hip_bfloat16 h = __float2bfloat16(v);
  return *reinterpret_cast<unsigned short*>(&h);
}

__device__ __forceinline__ unsigned int pk2(float lo, float hi) {
  return (unsigned int)bf16b(lo) | ((unsigned int)bf16b(hi) << 16);
}

// ---- K0: block 0 = CSR; blocks 1..200 = x transpose ----
__global__ __launch_bounds__(1024) void k_prep(
    const int* __restrict__ erow, const int* __restrict__ ecol,
    const float* __restrict__ eval, const float* __restrict__ x,
    int* __restrict__ row_ptr, int* __restrict__ col_s, float* __restrict__ val_s,
    float* __restrict__ xT) {
  const int t = threadIdx.x;
  if (blockIdx.x == 0) {
    __shared__ int cnt[N_];
    __shared__ int off[N_];
    __shared__ int bufA[1024];
    __shared__ int bufB[1024];
    if (t < N_) cnt[t] = 0;
    __syncthreads();
    for (int e = t; e < E_; e += 1024) atomicAdd(&cnt[erow[e]], 1);
    __syncthreads();
    bufA[t] = (t < N_) ? cnt[t] : 0;
    __syncthreads();
    int* src = bufA; int* dst = bufB;
    for (int d = 1; d < 1024; d <<= 1) {
      int v = src[t];
      if (t >= d) v += src[t - d];
      dst[t] = v;
      __syncthreads();
      int* tmp = src; src = dst; dst = tmp;
    }
    if (t < N_) {
      int ex = src[t] - cnt[t];
      off[t] = ex;
      row_ptr[t] = ex;
    }
    if (t == 0) row_ptr[N_] = E_;
    __syncthreads();
    for (int e = t; e < E_; e += 1024) {
      int r = erow[e];
      int p = atomicAdd(&off[r], 1);
      col_s[p] = ecol[e];
      val_s[p] = eval[e];
    }
  } else {
    __shared__ float tile[32][33];
    int bid = blockIdx.x - 1;
    int n0 = (bid % 25) * 32, b0 = (bid / 25) * 32;
    int ni = t & 31, bi = t >> 5;
    int n = n0 + ni;
    if (n < N_) tile[ni][bi] = x[(b0 + bi) * N_ + n];
    __syncthreads();
    int nj = t >> 5, bj = t & 31;
    int nw = n0 + nj;
    if (nw < N_) xT[nw * B_ + b0 + bj] = tile[nj][bj];
  }
}

// ---- K1: blocks [0,784): spmm1 -> agg1[n][b] (f32 scalar per node)
//      blocks [784,2352): Wf1 cvt+T part1 (k in [0,12544), 64x64 tiles) ----
__global__ __launch_bounds__(256) void k_gc1(
    const float* __restrict__ xT, const int* __restrict__ row_ptr,
    const int* __restrict__ col_s, const float* __restrict__ val_s,
    const float* __restrict__ Wf1, __hip_bfloat16* __restrict__ wf1t,
    float* __restrict__ agg1) {
  __shared__ union {
    struct { int lc[64]; float lv[64]; } g;
    float tile[64][65];
  } sm;
  int t = threadIdx.x;
  if (blockIdx.x < N_) {
    int n = blockIdx.x;
    int e0 = row_ptr[n], deg = row_ptr[n + 1] - e0;
    float agg = 0.f;
    for (int base = 0; base < deg; base += 64) {
      int m = min(64, deg - base);
      __syncthreads();
      if (t < m) { sm.g.lc[t] = col_s[e0 + base + t]; sm.g.lv[t] = val_s[e0 + base + t]; }
      __syncthreads();
      int e = 0;
      for (; e + 4 <= m; e += 4) {
        float x0 = xT[sm.g.lc[e + 0] * B_ + t];
        float x1 = xT[sm.g.lc[e + 1] * B_ + t];
        float x2 = xT[sm.g.lc[e + 2] * B_ + t];
        float x3 = xT[sm.g.lc[e + 3] * B_ + t];
        agg = fmaf(sm.g.lv[e + 0], x0, agg);
        agg = fmaf(sm.g.lv[e + 1], x1, agg);
        agg = fmaf(sm.g.lv[e + 2], x2, agg);
        agg = fmaf(sm.g.lv[e + 3], x3, agg);
      }
      for (; e < m; ++e)
        agg = fmaf(sm.g.lv[e], xT[sm.g.lc[e] * B_ + t], agg);
    }
    agg1[n * B_ + t] = agg;
  } else {
    // Wf1 transpose part1: 196 k-tiles x 8 n-tiles of 64x64, k0 in [0, 12544)
    int bid = blockIdx.x - N_;                 // 0..1567
    int k0 = (bid % 196) * 64, n0 = (bid / 196) * 64;
#pragma unroll
    for (int it = 0; it < 16; ++it) {
      int idx = it * 256 + t;
      int kk = idx >> 6, nn = idx & 63;
      sm.tile[kk][nn] = Wf1[(size_t)(k0 + kk) * H_ + n0 + nn];
    }
    __syncthreads();
#pragma unroll
    for (int it = 0; it < 8; ++it) {
      int idx = it * 256 + t;
      int nn = idx >> 5, kp = idx & 31;
      unsigned int v = pk2(sm.tile[2 * kp][nn], sm.tile[2 * kp + 1][nn]);
      *reinterpret_cast<unsigned int*>(
          wf1t + (size_t)(n0 + nn) * NK + k0 + 2 * kp) = v;
    }
  }
}

// ---- K2: blocks [0,3136): spmm2 via SCALAR gather + in-register h recompute
//          (h1[n][b][c] = elu(agg1[n][b]*W1[c]+b1[c]), rank-1 since F=1)
//          + W2 + elu -> flat.  4B gather per edge-lane (6.4MB total, L2-hot)
//      blocks [3136,9408): Wf1 cvt+T part2 (k in [12544,25088), 32x32 tiles) ----
__global__ __launch_bounds__(64) void k_gc2(
    const float* __restrict__ agg1, const int* __restrict__ row_ptr,
    const int* __restrict__ col_s, const float* __restrict__ val_s,
    const float* __restrict__ W1, const float* __restrict__ b1,
    const float* __restrict__ W2, const float* __restrict__ b2,
    const float* __restrict__ Wf1, __hip_bfloat16* __restrict__ wf1t,
    __hip_bfloat16* __restrict__ flat) {
  __shared__ union {
    struct { int lc[64]; float lv[64]; } g;
    float tile[32][33];
  } sm;
  int bid = blockIdx.x;
  int t = threadIdx.x;
  if (bid < N_ * 4) {
    int q = bid & 3;
    int n = bid >> 2;
    int tb = q * 64 + t;
    int e0 = row_ptr[n], deg = row_ptr[n + 1] - e0;
    // W1/b1 are wave-uniform reads -> SGPRs (keeps VGPR pressure at acc[32]+few)
    float w1r[C_], b1r[C_];
#pragma unroll
    for (int c = 0; c < C_; ++c) { w1r[c] = W1[c]; b1r[c] = b1[c]; }
    float acc[C_];
#pragma unroll
    for (int c = 0; c < C_; ++c) acc[c] = 0.f;
    for (int base = 0; base < deg; base += 64) {
      int m = min(64, deg - base);
      __syncthreads();
      if (t < m) { sm.g.lc[t] = col_s[e0 + base + t]; sm.g.lv[t] = val_s[e0 + base + t]; }
      __syncthreads();
      int e = 0;
      for (; e + 4 <= m; e += 4) {
        float s0 = agg1[sm.g.lc[e + 0] * B_ + tb];
        float s1 = agg1[sm.g.lc[e + 1] * B_ + tb];
        float s2 = agg1[sm.g.lc[e + 2] * B_ + tb];
        float s3 = agg1[sm.g.lc[e + 3] * B_ + tb];
        float v0 = sm.g.lv[e + 0], v1 = sm.g.lv[e + 1];
        float v2 = sm.g.lv[e + 2], v3 = sm.g.lv[e + 3];
#pragma unroll
        for (int c = 0; c < C_; ++c) {
          acc[c] = fmaf(v0, elu1(fmaf(s0, w1r[c], b1r[c])), acc[c]);
          acc[c] = fmaf(v1, elu1(fmaf(s1, w1r[c], b1r[c])), acc[c]);
          acc[c] = fmaf(v2, elu1(fmaf(s2, w1r[c], b1r[c])), acc[c]);
          acc[c] = fmaf(v3, elu1(fmaf(s3, w1r[c], b1r[c])), acc[c]);
        }
      }
      for (; e < m; ++e) {
        float s0 = agg1[sm.g.lc[e] * B_ + tb];
        float v0 = sm.g.lv[e];
#pragma unroll
        for (int c = 0; c < C_; ++c)
          acc[c] = fmaf(v0, elu1(fmaf(s0, w1r[c], b1r[c])), acc[c]);
      }
    }
    // W2 apply (uniform scalar loads) + elu + bf16 pack
    union { unsigned int u[16]; uint4 v[4]; } ob;
#pragma unroll
    for (int c2 = 0; c2 < C_; c2 += 2) {
      float o0 = b2[c2], o1 = b2[c2 + 1];
#pragma unroll
      for (int c = 0; c < C_; ++c) {
        o0 = fmaf(acc[c], W2[c * C_ + c2], o0);
        o1 = fmaf(acc[c], W2[c * C_ + c2 + 1], o1);
      }
      ob.u[c2 >> 1] = pk2(elu1(o0), elu1(o1));
    }
    uint4* dst = reinterpret_cast<uint4*>(flat + (size_t)tb * NK + n * C_);
#pragma unroll
    for (int j = 0; j < 4; ++j) dst[j] = ob.v[j];
  } else {
    // Wf1 transpose part2: 392 k-tiles x 16 n-tiles of 32x32, k0 in [12544, NK)
    int bid2 = bid - N_ * 4;                   // 0..6271
    int k0 = 12544 + (bid2 % 392) * 32, n0 = (bid2 / 392) * 32;
#pragma unroll
    for (int it = 0; it < 16; ++it) {
      int idx = it * 64 + t;
      int kk = idx >> 5, nn = idx & 31;
      sm.tile[kk][nn] = Wf1[(size_t)(k0 + kk) * H_ + n0 + nn];
    }
    __syncthreads();
#pragma unroll
    for (int it = 0; it < 8; ++it) {
      int idx = it * 64 + t;
      int nn = idx >> 4, kp = idx & 15;
      unsigned int v = pk2(sm.tile[2 * kp][nn], sm.tile[2 * kp + 1][nn]);
      *reinterpret_cast<unsigned int*>(
          wf1t + (size_t)(n0 + nn) * NK + k0 + 2 * kp) = v;
    }
  }
}

// ---------------- K3: fc1 split-K MFMA GEMM via global_load_lds pipeline ----------
// (unchanged from round 10 -- verified working)
__global__ __launch_bounds__(256, 2) void k_fc1(
    const __hip_bfloat16* __restrict__ flat, const __hip_bfloat16* __restrict__ wf1t,
    float* __restrict__ partial) {
  __shared__ unsigned char lds[3 * 24576];
  int raw = blockIdx.x;
  int bid = (raw & 7) * 56 + (raw >> 3);      // bijective XCD swizzle (448 = 8*56)
  int s = bid >> 4, r16 = bid & 15;
  int m0 = (r16 & 1) * 128;
  int n0 = (r16 >> 1) * 64;
  int k0 = s * 896;
  int tid = threadIdx.x;
  int w = tid >> 6, l = tid & 63;
  int r = l & 15, g = l >> 4;

  const __hip_bfloat16* src[6];
  int ldsoff[6];
#pragma unroll
  for (int j = 0; j < 6; ++j) {
    int reg = w * 6 + j;
    ldsoff[j] = reg * 1024 + l * 16;
    if (reg < 16) {
      int fmg = reg >> 1, ks = reg & 1;
      src[j] = flat + (size_t)(m0 + fmg * 16 + r) * NK + (k0 + ks * 32 + g * 8);
    } else {
      int fng = (reg - 16) >> 1, ks = reg & 1;
      src[j] = wf1t + (size_t)(n0 + fng * 16 + r) * NK + (k0 + ks * 32 + g * 8);
    }
  }

  f32x4 acc[4][2];
#pragma unroll
  for (int i = 0; i < 4; ++i)
#pragma unroll
    for (int j = 0; j < 2; ++j) acc[i][j] = (f32x4){0.f, 0.f, 0.f, 0.f};

#define GLOAD_LDS(gp, lp)                                                     \
  __builtin_amdgcn_global_load_lds(                                           \
      (const __attribute__((address_space(1))) unsigned int*)(gp),            \
      (__attribute__((address_space(3))) unsigned int*)(lp), 16, 0, 0)
#define STAGE(t, buf) do {                                                    \
    _Pragma("unroll")                                                         \
    for (int j = 0; j < 6; ++j)                                               \
      GLOAD_LDS(src[j] + (t) * 64, &lds[(buf) * 24576 + ldsoff[j]]);          \
  } while (0)
#define VWAIT(n) do {                                                         \
    asm volatile("s_waitcnt vmcnt(%0)" :: "n"(n) : "memory");                 \
    __builtin_amdgcn_sched_barrier(0);                                        \
  } while (0)
#define BAR() do {                                                            \
    __builtin_amdgcn_s_barrier();                                             \
    __builtin_amdgcn_sched_barrier(0);                                        \
  } while (0)
#define COMPUTE(buf) do {                                                     \
    const unsigned char* bb = &lds[(buf) * 24576];                            \
    short8 af[4][2], bf[2][2];                                                \
    _Pragma("unroll")                                                         \
    for (int fm = 0; fm < 4; ++fm)                                            \
      _Pragma("unroll")                                                       \
      for (int ks = 0; ks < 2; ++ks)                                          \
        af[fm][ks] = *reinterpret_cast<const short8*>(                        \
            bb + (((4 * (w & 1) + fm) * 2 + ks) << 10) + l * 16);             \
    _Pragma("unroll")                                                         \
    for (int fn = 0; fn < 2; ++fn)                                            \
      _Pragma("unroll")                                                       \
      for (int ks = 0; ks < 2; ++ks)                                          \
        bf[fn][ks] = *reinterpret_cast<const short8*>(                        \
            bb + ((16 + (2 * (w >> 1) + fn) * 2 + ks) << 10) + l * 16);       \
    _Pragma("unroll")                                                         \
    for (int ks = 0; ks < 2; ++ks)                                            \
      _Pragma("unroll")                                                       \
      for (int fn = 0; fn < 2; ++fn)                                          \
        _Pragma("unroll")                                                     \
        for (int fm = 0; fm < 4; ++fm)                                        \
          acc[fm][fn] = __builtin_amdgcn_mfma_f32_16x16x32_bf16(              \
              af[fm][ks], bf[fn][ks], acc[fm][fn], 0, 0, 0);                  \
  } while (0)
#define STEP(t) do {                                                          \
    VWAIT((t) < 13 ? 6 : 0);                                                  \
    BAR();                                                                    \
    if ((t) + 2 <= 13) STAGE((t) + 2, ((t) + 2) % 3);                         \
    COMPUTE((t) % 3);                                                         \
  } while (0)

  STAGE(0, 0);
  STAGE(1, 1);
  STEP(0);  STEP(1);  STEP(2);  STEP(3);  STEP(4);  STEP(5);  STEP(6);
  STEP(7);  STEP(8);  STEP(9);  STEP(10); STEP(11); STEP(12); STEP(13);

#undef GLOAD_LDS
#undef STAGE
#undef VWAIT
#undef BAR
#undef COMPUTE
#undef STEP

  int wm = (w & 1) * 64, wn = (w >> 1) * 32;
  float* p = partial + (size_t)s * (256 * 512);
#pragma unroll
  for (int fm = 0; fm < 4; ++fm)
#pragma unroll
    for (int fn = 0; fn < 2; ++fn)
#pragma unroll
      for (int q = 0; q < 4; ++q) {
        int m = m0 + wm + fm * 16 + g * 4 + q;
        int n = n0 + wn + fn * 16 + r;
        p[m * 512 + n] = acc[fm][fn][q];
      }
}

// ---------------- K4: reduce partials + bias + relu + fc2 + softmax ----------------
__global__ __launch_bounds__(512) void k_head(
    const float* __restrict__ partial, const float* __restrict__ bf1,
    const float* __restrict__ Wf2, const float* __restrict__ bf2,
    float* __restrict__ out) {
  __shared__ float red[8][12];
  int b = blockIdx.x;
  int t = threadIdx.x;
  float v = bf1[t];
#pragma unroll
  for (int s = 0; s < S_SPLIT; ++s)
    v += partial[(size_t)s * (256 * 512) + b * 512 + t];
  v = fmaxf(v, 0.f);
  float pacc[10];
#pragma unroll
  for (int j = 0; j < 10; ++j) pacc[j] = v * Wf2[t * 10 + j];
#pragma unroll
  for (int j = 0; j < 10; ++j)
#pragma unroll
    for (int d = 32; d > 0; d >>= 1)
      pacc[j] += __shfl_down(pacc[j], d);
  int wv = t >> 6, ln = t & 63;
  if (ln == 0) {
#pragma unroll
    for (int j = 0; j < 10; ++j) red[wv][j] = pacc[j];
  }
  __syncthreads();
  if (t == 0) {
    float lg[10];
    float m = -1e30f;
#pragma unroll
    for (int j = 0; j < 10; ++j) {
      float z = bf2[j];
#pragma unroll
      for (int wq = 0; wq < 8; ++wq) z += red[wq][j];
      lg[j] = z;
      m = fmaxf(m, z);
    }
    float sum = 0.f;
#pragma unroll
    for (int j = 0; j < 10; ++j) { lg[j] = __expf(lg[j] - m); sum += lg[j]; }
    float inv = 1.f / sum;
#pragma unroll
    for (int j = 0; j < 10; ++j) out[b * 10 + j] = lg[j] * inv;
  }
}

extern "C" void kernel_launch(void* const* d_in, const int* in_sizes, int n_in,
                              void* d_out, int out_size, void* d_ws, size_t ws_size,
                              hipStream_t stream) {
  const float* x    = (const float*)d_in[0];
  const int*   erow = (const int*)d_in[1];
  const int*   ecol = (const int*)d_in[2];
  const float* ev   = (const float*)d_in[3];
  const float* W1   = (const float*)d_in[4];
  const float* b1   = (const float*)d_in[5];
  const float* W2   = (const float*)d_in[6];
  const float* b2   = (const float*)d_in[7];
  const float* Wf1  = (const float*)d_in[8];
  const float* bf1  = (const float*)d_in[9];
  const float* Wf2  = (const float*)d_in[10];
  const float* bf2  = (const float*)d_in[11];
  float* out = (float*)d_out;

  const size_t partial_bytes = (size_t)S_SPLIT * 256 * 512 * 4;   // 14,680,064
  const size_t flat_bytes    = (size_t)B_ * NK * 2;               // 12,845,056
  const size_t wf1t_bytes    = (size_t)H_ * NK * 2;               // 25,690,112

  // ws layout (~53.3 MB):
  //   [0, 0.80M)           xT f32            (dead after gc1)
  //   [0.80M, 1.61M)       agg1 f32          (dead after gc2)
  //   [0, 14.68M)          partial           (fc1 writes after xT/agg1 dead)
  //   [14.68M, 27.53M)     flat bf16
  //   [27.53M, 53.22M)     wf1t bf16 (Wf1 transposed)
  //   tail                 CSR (row_ptr, col_s, val_s)
  char* ws = (char*)d_ws;
  float* partial = (float*)ws;
  float* xT   = (float*)ws;
  float* agg1 = (float*)(ws + 802816);
  __hip_bfloat16* flat = (__hip_bfloat16*)(ws + partial_bytes);
  __hip_bfloat16* wf1t = (__hip_bfloat16*)(ws + partial_bytes + flat_bytes);
  char* tail = ws + partial_bytes + flat_bytes + wf1t_bytes;
  int*   row_ptr = (int*)tail;
  int*   col_s   = (int*)(tail + 3152);
  float* val_s   = (float*)(tail + 3152 + E_ * 4);

  hipLaunchKernelGGL(k_prep, dim3(1 + 200), dim3(1024), 0, stream,
                     erow, ecol, ev, x, row_ptr, col_s, val_s, xT);
  hipLaunchKernelGGL(k_gc1, dim3(N_ + 196 * 8), dim3(256), 0, stream,
                     xT, row_ptr, col_s, val_s, Wf1, wf1t, agg1);
  hipLaunchKernelGGL(k_gc2, dim3(N_ * 4 + 392 * 16), dim3(64), 0, stream,
                     agg1, row_ptr, col_s, val_s, W1, b1, W2, b2, Wf1, wf1t, flat);
  hipLaunchKernelGGL(k_fc1, dim3(S_SPLIT * 16), dim3(256), 0, stream,
                     flat, wf1t, partial);
  hipLaunchKernelGGL(k_head, dim3(B_), dim3(512), 0, stream,
                     partial, bf1, Wf2, bf2, out);
}

// Round 24
// 80.027 us; speedup vs baseline: 1.7859x; 1.0696x over previous
//
#include <hip/hip_runtime.h>
#include <hip/hip_bf16.h>

#define B_ 256
#define N_ 784
#define E_ 6272
#define C_ 32
#define H_ 512
#define NK 25088            // N_*C_  (K of fc1; wf1t row stride)
#define S_SPLIT 28

typedef __attribute__((ext_vector_type(8))) short short8;
typedef __attribute__((ext_vector_type(4))) float f32x4;

__device__ __forceinline__ float elu1(float v) {
  return v > 0.f ? v : (__expf(v) - 1.f);
}

__device__ __forceinline__ unsigned short bf16b(float v) {
  __hip_bfloat16 h = __float2bfloat16(v);
  return *reinterpret_cast<unsigned short*>(&h);
}

__device__ __forceinline__ unsigned int pk2(float lo, float hi) {
  return (unsigned int)bf16b(lo) | ((unsigned int)bf16b(hi) << 16);
}

// ---- K0: block 0 = CSR; blocks 1..200 = x transpose ----
__global__ __launch_bounds__(1024) void k_prep(
    const int* __restrict__ erow, const int* __restrict__ ecol,
    const float* __restrict__ eval, const float* __restrict__ x,
    int* __restrict__ row_ptr, int* __restrict__ col_s, float* __restrict__ val_s,
    float* __restrict__ xT) {
  const int t = threadIdx.x;
  if (blockIdx.x == 0) {
    __shared__ int cnt[N_];
    __shared__ int off[N_];
    __shared__ int bufA[1024];
    __shared__ int bufB[1024];
    if (t < N_) cnt[t] = 0;
    __syncthreads();
    for (int e = t; e < E_; e += 1024) atomicAdd(&cnt[erow[e]], 1);
    __syncthreads();
    bufA[t] = (t < N_) ? cnt[t] : 0;
    __syncthreads();
    int* src = bufA; int* dst = bufB;
    for (int d = 1; d < 1024; d <<= 1) {
      int v = src[t];
      if (t >= d) v += src[t - d];
      dst[t] = v;
      __syncthreads();
      int* tmp = src; src = dst; dst = tmp;
    }
    if (t < N_) {
      int ex = src[t] - cnt[t];
      off[t] = ex;
      row_ptr[t] = ex;
    }
    if (t == 0) row_ptr[N_] = E_;
    __syncthreads();
    for (int e = t; e < E_; e += 1024) {
      int r = erow[e];
      int p = atomicAdd(&off[r], 1);
      col_s[p] = ecol[e];
      val_s[p] = eval[e];
    }
  } else {
    __shared__ float tile[32][33];
    int bid = blockIdx.x - 1;
    int n0 = (bid % 25) * 32, b0 = (bid / 25) * 32;
    int ni = t & 31, bi = t >> 5;
    int n = n0 + ni;
    if (n < N_) tile[ni][bi] = x[(b0 + bi) * N_ + n];
    __syncthreads();
    int nj = t >> 5, bj = t & 31;
    int nw = n0 + nj;
    if (nw < N_) xT[nw * B_ + b0 + bj] = tile[nj][bj];
  }
}

// ---- K1: blocks [0,784): spmm1 -> agg1[n][b] (f32 scalar per node)
//      blocks [784,2352): Wf1 cvt+T part1 (k in [0,12544), 64x64 tiles) ----
__global__ __launch_bounds__(256) void k_gc1(
    const float* __restrict__ xT, const int* __restrict__ row_ptr,
    const int* __restrict__ col_s, const float* __restrict__ val_s,
    const float* __restrict__ Wf1, __hip_bfloat16* __restrict__ wf1t,
    float* __restrict__ agg1) {
  __shared__ union {
    struct { int lc[64]; float lv[64]; } g;
    float tile[64][65];
  } sm;
  int t = threadIdx.x;
  if (blockIdx.x < N_) {
    int n = blockIdx.x;
    int e0 = row_ptr[n], deg = row_ptr[n + 1] - e0;
    float agg = 0.f;
    for (int base = 0; base < deg; base += 64) {
      int m = min(64, deg - base);
      __syncthreads();
      if (t < m) { sm.g.lc[t] = col_s[e0 + base + t]; sm.g.lv[t] = val_s[e0 + base + t]; }
      __syncthreads();
      int e = 0;
      for (; e + 4 <= m; e += 4) {
        float x0 = xT[sm.g.lc[e + 0] * B_ + t];
        float x1 = xT[sm.g.lc[e + 1] * B_ + t];
        float x2 = xT[sm.g.lc[e + 2] * B_ + t];
        float x3 = xT[sm.g.lc[e + 3] * B_ + t];
        agg = fmaf(sm.g.lv[e + 0], x0, agg);
        agg = fmaf(sm.g.lv[e + 1], x1, agg);
        agg = fmaf(sm.g.lv[e + 2], x2, agg);
        agg = fmaf(sm.g.lv[e + 3], x3, agg);
      }
      for (; e < m; ++e)
        agg = fmaf(sm.g.lv[e], xT[sm.g.lc[e] * B_ + t], agg);
    }
    agg1[n * B_ + t] = agg;
  } else {
    // Wf1 transpose part1: 196 k-tiles x 8 n-tiles of 64x64, k0 in [0, 12544)
    int bid = blockIdx.x - N_;                 // 0..1567
    int k0 = (bid % 196) * 64, n0 = (bid / 196) * 64;
#pragma unroll
    for (int it = 0; it < 16; ++it) {
      int idx = it * 256 + t;
      int kk = idx >> 6, nn = idx & 63;
      sm.tile[kk][nn] = Wf1[(size_t)(k0 + kk) * H_ + n0 + nn];
    }
    __syncthreads();
#pragma unroll
    for (int it = 0; it < 8; ++it) {
      int idx = it * 256 + t;
      int nn = idx >> 5, kp = idx & 31;
      unsigned int v = pk2(sm.tile[2 * kp][nn], sm.tile[2 * kp + 1][nn]);
      *reinterpret_cast<unsigned int*>(
          wf1t + (size_t)(n0 + nn) * NK + k0 + 2 * kp) = v;
    }
  }
}

// ---- K2: blocks [0,3136): spmm2 via SCALAR gather + in-register h recompute
//      blocks [3136,9408): Wf1 cvt+T part2 (k in [12544,25088), 32x32 tiles) ----
__global__ __launch_bounds__(64) void k_gc2(
    const float* __restrict__ agg1, const int* __restrict__ row_ptr,
    const int* __restrict__ col_s, const float* __restrict__ val_s,
    const float* __restrict__ W1, const float* __restrict__ b1,
    const float* __restrict__ W2, const float* __restrict__ b2,
    const float* __restrict__ Wf1, __hip_bfloat16* __restrict__ wf1t,
    __hip_bfloat16* __restrict__ flat) {
  __shared__ union {
    struct { int lc[64]; float lv[64]; } g;
    float tile[32][33];
  } sm;
  int bid = blockIdx.x;
  int t = threadIdx.x;
  if (bid < N_ * 4) {
    int q = bid & 3;
    int n = bid >> 2;
    int tb = q * 64 + t;
    int e0 = row_ptr[n], deg = row_ptr[n + 1] - e0;
    float w1r[C_], b1r[C_];
#pragma unroll
    for (int c = 0; c < C_; ++c) { w1r[c] = W1[c]; b1r[c] = b1[c]; }
    float acc[C_];
#pragma unroll
    for (int c = 0; c < C_; ++c) acc[c] = 0.f;
    for (int base = 0; base < deg; base += 64) {
      int m = min(64, deg - base);
      __syncthreads();
      if (t < m) { sm.g.lc[t] = col_s[e0 + base + t]; sm.g.lv[t] = val_s[e0 + base + t]; }
      __syncthreads();
      int e = 0;
      for (; e + 4 <= m; e += 4) {
        float s0 = agg1[sm.g.lc[e + 0] * B_ + tb];
        float s1 = agg1[sm.g.lc[e + 1] * B_ + tb];
        float s2 = agg1[sm.g.lc[e + 2] * B_ + tb];
        float s3 = agg1[sm.g.lc[e + 3] * B_ + tb];
        float v0 = sm.g.lv[e + 0], v1 = sm.g.lv[e + 1];
        float v2 = sm.g.lv[e + 2], v3 = sm.g.lv[e + 3];
#pragma unroll
        for (int c = 0; c < C_; ++c) {
          acc[c] = fmaf(v0, elu1(fmaf(s0, w1r[c], b1r[c])), acc[c]);
          acc[c] = fmaf(v1, elu1(fmaf(s1, w1r[c], b1r[c])), acc[c]);
          acc[c] = fmaf(v2, elu1(fmaf(s2, w1r[c], b1r[c])), acc[c]);
          acc[c] = fmaf(v3, elu1(fmaf(s3, w1r[c], b1r[c])), acc[c]);
        }
      }
      for (; e < m; ++e) {
        float s0 = agg1[sm.g.lc[e] * B_ + tb];
        float v0 = sm.g.lv[e];
#pragma unroll
        for (int c = 0; c < C_; ++c)
          acc[c] = fmaf(v0, elu1(fmaf(s0, w1r[c], b1r[c])), acc[c]);
      }
    }
    union { unsigned int u[16]; uint4 v[4]; } ob;
#pragma unroll
    for (int c2 = 0; c2 < C_; c2 += 2) {
      float o0 = b2[c2], o1 = b2[c2 + 1];
#pragma unroll
      for (int c = 0; c < C_; ++c) {
        o0 = fmaf(acc[c], W2[c * C_ + c2], o0);
        o1 = fmaf(acc[c], W2[c * C_ + c2 + 1], o1);
      }
      ob.u[c2 >> 1] = pk2(elu1(o0), elu1(o1));
    }
    uint4* dst = reinterpret_cast<uint4*>(flat + (size_t)tb * NK + n * C_);
#pragma unroll
    for (int j = 0; j < 4; ++j) dst[j] = ob.v[j];
  } else {
    // Wf1 transpose part2: 392 k-tiles x 16 n-tiles of 32x32, k0 in [12544, NK)
    int bid2 = bid - N_ * 4;                   // 0..6271
    int k0 = 12544 + (bid2 % 392) * 32, n0 = (bid2 / 392) * 32;
#pragma unroll
    for (int it = 0; it < 16; ++it) {
      int idx = it * 64 + t;
      int kk = idx >> 5, nn = idx & 31;
      sm.tile[kk][nn] = Wf1[(size_t)(k0 + kk) * H_ + n0 + nn];
    }
    __syncthreads();
#pragma unroll
    for (int it = 0; it < 8; ++it) {
      int idx = it * 64 + t;
      int nn = idx >> 4, kp = idx & 15;
      unsigned int v = pk2(sm.tile[2 * kp][nn], sm.tile[2 * kp + 1][nn]);
      *reinterpret_cast<unsigned int*>(
          wf1t + (size_t)(n0 + nn) * NK + k0 + 2 * kp) = v;
    }
  }
}

// ---- K3: fc1 split-K MFMA GEMM, BM=128 x BN=128, 8 waves, 3-buffer pipeline ----
// grid = 28 s x 2 mt x 4 nt = 224 (XCD-swizzled); 512 threads = 8 waves (2m x 4n),
// wave tile 64x32, acc[4][2]. 32 x 1KB fragment regions per buffer (A:0-15, B:16-31);
// wave w stages regions w*4..w*4+3 -> VWAIT(4). Same depth-2 counted-vmcnt schedule
// as the verified 448-block version; staging traffic 150MB -> 100MB.
__global__ __launch_bounds__(512, 1) void k_fc1(
    const __hip_bfloat16* __restrict__ flat, const __hip_bfloat16* __restrict__ wf1t,
    float* __restrict__ partial) {
  __shared__ unsigned char lds[3 * 32768];
  int raw = blockIdx.x;
  int bid = (raw & 7) * 28 + (raw >> 3);      // bijective XCD swizzle (224 = 8*28)
  int s = bid >> 3, r8 = bid & 7;
  int m0 = (r8 & 1) * 128;
  int n0 = (r8 >> 1) * 128;
  int k0 = s * 896;
  int tid = threadIdx.x;
  int w = tid >> 6, l = tid & 63;
  int r = l & 15, g = l >> 4;

  // This wave's 4 staging regions (region ids w*4+j of 32).
  const __hip_bfloat16* src[4];
  int ldsoff[4];
#pragma unroll
  for (int j = 0; j < 4; ++j) {
    int reg = w * 4 + j;
    ldsoff[j] = reg * 1024 + l * 16;
    if (reg < 16) {
      int fmg = reg >> 1, ks = reg & 1;
      src[j] = flat + (size_t)(m0 + fmg * 16 + r) * NK + (k0 + ks * 32 + g * 8);
    } else {
      int fng = (reg - 16) >> 1, ks = reg & 1;
      src[j] = wf1t + (size_t)(n0 + fng * 16 + r) * NK + (k0 + ks * 32 + g * 8);
    }
  }

  f32x4 acc[4][2];
#pragma unroll
  for (int i = 0; i < 4; ++i)
#pragma unroll
    for (int j = 0; j < 2; ++j) acc[i][j] = (f32x4){0.f, 0.f, 0.f, 0.f};

#define GLOAD_LDS(gp, lp)                                                     \
  __builtin_amdgcn_global_load_lds(                                           \
      (const __attribute__((address_space(1))) unsigned int*)(gp),            \
      (__attribute__((address_space(3))) unsigned int*)(lp), 16, 0, 0)
#define STAGE(t, buf) do {                                                    \
    _Pragma("unroll")                                                         \
    for (int j = 0; j < 4; ++j)                                               \
      GLOAD_LDS(src[j] + (t) * 64, &lds[(buf) * 32768 + ldsoff[j]]);          \
  } while (0)
#define VWAIT(n) do {                                                         \
    asm volatile("s_waitcnt vmcnt(%0)" :: "n"(n) : "memory");                 \
    __builtin_amdgcn_sched_barrier(0);                                        \
  } while (0)
#define BAR() do {                                                            \
    __builtin_amdgcn_s_barrier();                                             \
    __builtin_amdgcn_sched_barrier(0);                                        \
  } while (0)
#define COMPUTE(buf) do {                                                     \
    const unsigned char* bb = &lds[(buf) * 32768];                            \
    short8 af[4][2], bf[2][2];                                                \
    _Pragma("unroll")                                                         \
    for (int fm = 0; fm < 4; ++fm)                                            \
      _Pragma("unroll")                                                       \
      for (int ks = 0; ks < 2; ++ks)                                          \
        af[fm][ks] = *reinterpret_cast<const short8*>(                        \
            bb + ((((w & 1) * 4 + fm) * 2 + ks) << 10) + l * 16);             \
    _Pragma("unroll")                                                         \
    for (int fn = 0; fn < 2; ++fn)                                            \
      _Pragma("unroll")                                                       \
      for (int ks = 0; ks < 2; ++ks)                                          \
        bf[fn][ks] = *reinterpret_cast<const short8*>(                        \
            bb + ((16 + ((w >> 1) * 2 + fn) * 2 + ks) << 10) + l * 16);       \
    _Pragma("unroll")                                                         \
    for (int ks = 0; ks < 2; ++ks)                                            \
      _Pragma("unroll")                                                       \
      for (int fn = 0; fn < 2; ++fn)                                          \
        _Pragma("unroll")                                                     \
        for (int fm = 0; fm < 4; ++fm)                                        \
          acc[fm][fn] = __builtin_amdgcn_mfma_f32_16x16x32_bf16(              \
              af[fm][ks], bf[fn][ks], acc[fm][fn], 0, 0, 0);                  \
  } while (0)
#define STEP(t) do {                                                          \
    VWAIT((t) < 13 ? 4 : 0);                                                  \
    BAR();                                                                    \
    if ((t) + 2 <= 13) STAGE((t) + 2, ((t) + 2) % 3);                         \
    COMPUTE((t) % 3);                                                         \
  } while (0)

  STAGE(0, 0);
  STAGE(1, 1);
  STEP(0);  STEP(1);  STEP(2);  STEP(3);  STEP(4);  STEP(5);  STEP(6);
  STEP(7);  STEP(8);  STEP(9);  STEP(10); STEP(11); STEP(12); STEP(13);

#undef GLOAD_LDS
#undef STAGE
#undef VWAIT
#undef BAR
#undef COMPUTE
#undef STEP

  int wm = (w & 1) * 64, wn = (w >> 1) * 32;
  float* p = partial + (size_t)s * (256 * 512);
#pragma unroll
  for (int fm = 0; fm < 4; ++fm)
#pragma unroll
    for (int fn = 0; fn < 2; ++fn)
#pragma unroll
      for (int q = 0; q < 4; ++q) {
        int m = m0 + wm + fm * 16 + g * 4 + q;
        int n = n0 + wn + fn * 16 + r;
        p[m * 512 + n] = acc[fm][fn][q];
      }
}

// ---------------- K4: reduce partials + bias + relu + fc2 + softmax ----------------
__global__ __launch_bounds__(512) void k_head(
    const float* __restrict__ partial, const float* __restrict__ bf1,
    const float* __restrict__ Wf2, const float* __restrict__ bf2,
    float* __restrict__ out) {
  __shared__ float red[8][12];
  int b = blockIdx.x;
  int t = threadIdx.x;
  float v = bf1[t];
#pragma unroll
  for (int s = 0; s < S_SPLIT; ++s)
    v += partial[(size_t)s * (256 * 512) + b * 512 + t];
  v = fmaxf(v, 0.f);
  float pacc[10];
#pragma unroll
  for (int j = 0; j < 10; ++j) pacc[j] = v * Wf2[t * 10 + j];
#pragma unroll
  for (int j = 0; j < 10; ++j)
#pragma unroll
    for (int d = 32; d > 0; d >>= 1)
      pacc[j] += __shfl_down(pacc[j], d);
  int wv = t >> 6, ln = t & 63;
  if (ln == 0) {
#pragma unroll
    for (int j = 0; j < 10; ++j) red[wv][j] = pacc[j];
  }
  __syncthreads();
  if (t == 0) {
    float lg[10];
    float m = -1e30f;
#pragma unroll
    for (int j = 0; j < 10; ++j) {
      float z = bf2[j];
#pragma unroll
      for (int wq = 0; wq < 8; ++wq) z += red[wq][j];
      lg[j] = z;
      m = fmaxf(m, z);
    }
    float sum = 0.f;
#pragma unroll
    for (int j = 0; j < 10; ++j) { lg[j] = __expf(lg[j] - m); sum += lg[j]; }
    float inv = 1.f / sum;
#pragma unroll
    for (int j = 0; j < 10; ++j) out[b * 10 + j] = lg[j] * inv;
  }
}

extern "C" void kernel_launch(void* const* d_in, const int* in_sizes, int n_in,
                              void* d_out, int out_size, void* d_ws, size_t ws_size,
                              hipStream_t stream) {
  const float* x    = (const float*)d_in[0];
  const int*   erow = (const int*)d_in[1];
  const int*   ecol = (const int*)d_in[2];
  const float* ev   = (const float*)d_in[3];
  const float* W1   = (const float*)d_in[4];
  const float* b1   = (const float*)d_in[5];
  const float* W2   = (const float*)d_in[6];
  const float* b2   = (const float*)d_in[7];
  const float* Wf1  = (const float*)d_in[8];
  const float* bf1  = (const float*)d_in[9];
  const float* Wf2  = (const float*)d_in[10];
  const float* bf2  = (const float*)d_in[11];
  float* out = (float*)d_out;

  const size_t partial_bytes = (size_t)S_SPLIT * 256 * 512 * 4;   // 14,680,064
  const size_t flat_bytes    = (size_t)B_ * NK * 2;               // 12,845,056
  const size_t wf1t_bytes    = (size_t)H_ * NK * 2;               // 25,690,112

  // ws layout (~53.3 MB):
  //   [0, 0.80M)           xT f32            (dead after gc1)
  //   [0.80M, 1.61M)       agg1 f32          (dead after gc2)
  //   [0, 14.68M)          partial           (fc1 writes after xT/agg1 dead)
  //   [14.68M, 27.53M)     flat bf16
  //   [27.53M, 53.22M)     wf1t bf16 (Wf1 transposed)
  //   tail                 CSR (row_ptr, col_s, val_s)
  char* ws = (char*)d_ws;
  float* partial = (float*)ws;
  float* xT   = (float*)ws;
  float* agg1 = (float*)(ws + 802816);
  __hip_bfloat16* flat = (__hip_bfloat16*)(ws + partial_bytes);
  __hip_bfloat16* wf1t = (__hip_bfloat16*)(ws + partial_bytes + flat_bytes);
  char* tail = ws + partial_bytes + flat_bytes + wf1t_bytes;
  int*   row_ptr = (int*)tail;
  int*   col_s   = (int*)(tail + 3152);
  float* val_s   = (float*)(tail + 3152 + E_ * 4);

  hipLaunchKernelGGL(k_prep, dim3(1 + 200), dim3(1024), 0, stream,
                     erow, ecol, ev, x, row_ptr, col_s, val_s, xT);
  hipLaunchKernelGGL(k_gc1, dim3(N_ + 196 * 8), dim3(256), 0, stream,
                     xT, row_ptr, col_s, val_s, Wf1, wf1t, agg1);
  hipLaunchKernelGGL(k_gc2, dim3(N_ * 4 + 392 * 16), dim3(64), 0, stream,
                     agg1, row_ptr, col_s, val_s, W1, b1, W2, b2, Wf1, wf1t, flat);
  hipLaunchKernelGGL(k_fc1, dim3(224), dim3(512), 0, stream,
                     flat, wf1t, partial);
  hipLaunchKernelGGL(k_head, dim3(B_), dim3(512), 0, stream,
                     partial, bf1, Wf2, bf2, out);
}